// Round 3
// baseline (107.699 us; speedup 1.0000x reference)
//
#include <hip/hip_runtime.h>

// Problem constants (from reference setup_inputs)
#define BB 8
#define CC 19
#define HH 512
#define WW 512
#define HW (HH * WW)            // 262144 = 2^18
#define NVOX (BB * HW)          // 2097152
#define NQUAD (NVOX / 4)        // 524288
#define BLOCK 256
#define GRID (NQUAD / BLOCK)    // 2048
#define NWAVE (BLOCK / 64)

// ---------------- main pass ----------------
// PRIV=true : write per-block partials to ws (no contended atomics)
// PRIV=false: legacy global-atomic path (fallback if ws too small)
template <bool PRIV>
__global__ __launch_bounds__(BLOCK, 2) void ce_pass1(
        const float* __restrict__ predict,
        const float* __restrict__ target,
        int* __restrict__ cnt_ws,      // PRIV: [CC][GRID]; else: [CC]
        float* __restrict__ sum_ws) {  // PRIV: [CC][GRID]; else: [CC]
    __shared__ int   s_cnt[NWAVE][CC];
    __shared__ float s_sum[NWAVE][CC];
    const int tid = threadIdx.x;
    const int wv  = tid >> 6;
    const int ln  = tid & 63;
    if (ln < CC) { s_cnt[wv][ln] = 0; s_sum[wv][ln] = 0.0f; }
    __syncthreads();

    // One quad (4 consecutive voxels) per thread; grid covers NQUAD exactly.
    const int q = blockIdx.x * BLOCK + tid;
    const long base = (long)q * 4;                 // voxel index
    const int  b    = (int)(base >> 18);           // / HW
    const int  hw   = (int)(base & (HW - 1));
    const float* tp = target  + (long)b * CC * HW + hw;
    const float* pp = predict + (long)b * CC * HW + hw;

    float4 t[CC], p[CC];
    #pragma unroll
    for (int c = 0; c < CC; ++c)
        t[c] = *reinterpret_cast<const float4*>(tp + (long)c * HW);
    #pragma unroll
    for (int c = 0; c < CC; ++c)
        p[c] = *reinterpret_cast<const float4*>(pp + (long)c * HW);

    // argmax over target (first-occurrence tie-break via strict >)
    float tmax[4] = {-1e30f, -1e30f, -1e30f, -1e30f};
    int   targ[4] = {0, 0, 0, 0};
    #pragma unroll
    for (int c = 0; c < CC; ++c) {
        if (t[c].x > tmax[0]) { tmax[0] = t[c].x; targ[0] = c; }
        if (t[c].y > tmax[1]) { tmax[1] = t[c].y; targ[1] = c; }
        if (t[c].z > tmax[2]) { tmax[2] = t[c].z; targ[2] = c; }
        if (t[c].w > tmax[3]) { tmax[3] = t[c].w; targ[3] = c; }
    }

    // max over predict
    float m[4] = {-1e30f, -1e30f, -1e30f, -1e30f};
    #pragma unroll
    for (int c = 0; c < CC; ++c) {
        m[0] = fmaxf(m[0], p[c].x);
        m[1] = fmaxf(m[1], p[c].y);
        m[2] = fmaxf(m[2], p[c].z);
        m[3] = fmaxf(m[3], p[c].w);
    }

    // sum of exp + select p[targ]
    float s[4]   = {0.0f, 0.0f, 0.0f, 0.0f};
    float ptg[4] = {0.0f, 0.0f, 0.0f, 0.0f};
    #pragma unroll
    for (int c = 0; c < CC; ++c) {
        s[0] += __expf(p[c].x - m[0]);  if (c == targ[0]) ptg[0] = p[c].x;
        s[1] += __expf(p[c].y - m[1]);  if (c == targ[1]) ptg[1] = p[c].y;
        s[2] += __expf(p[c].z - m[2]);  if (c == targ[2]) ptg[2] = p[c].z;
        s[3] += __expf(p[c].w - m[3]);  if (c == targ[3]) ptg[3] = p[c].w;
    }

    #pragma unroll
    for (int j = 0; j < 4; ++j) {
        const float ce = __logf(s[j]) + m[j] - ptg[j];   // logsumexp - p[argmax]
        atomicAdd(&s_cnt[wv][targ[j]], 1);
        atomicAdd(&s_sum[wv][targ[j]], ce);
    }
    __syncthreads();
    if (tid < CC) {
        int cs = 0; float ss = 0.0f;
        #pragma unroll
        for (int w = 0; w < NWAVE; ++w) { cs += s_cnt[w][tid]; ss += s_sum[w][tid]; }
        if (PRIV) {
            cnt_ws[tid * GRID + blockIdx.x] = cs;   // private slot, no contention
            sum_ws[tid * GRID + blockIdx.x] = ss;
        } else {
            atomicAdd(&cnt_ws[tid], cs);
            atomicAdd(&sum_ws[tid], ss);
        }
    }
}

// ---------------- reduction over per-block partials ----------------
__global__ void ce_reduce(const int* __restrict__ cnt,
                          const float* __restrict__ sum,
                          float* __restrict__ out) {
    __shared__ int   s_n[CC];
    __shared__ float s_s[CC];
    const int tid = threadIdx.x;
    const int wv  = tid >> 6;
    const int ln  = tid & 63;
    for (int c = wv; c < CC; c += NWAVE) {
        int   n = 0; float s = 0.0f;
        for (int i = ln; i < GRID; i += 64) {
            n += cnt[c * GRID + i];
            s += sum[c * GRID + i];
        }
        #pragma unroll
        for (int o = 32; o > 0; o >>= 1) {
            n += __shfl_down(n, o);
            s += __shfl_down(s, o);
        }
        if (ln == 0) { s_n[c] = n; s_s[c] = s; }
    }
    __syncthreads();
    if (tid == 0) {
        double tot = 0.0;
        for (int c = 0; c < CC; ++c) {
            const int n = s_n[c];
            float w = 1.0f;
            if (n > 0) w = logf((float)NVOX / (float)n);
            tot += (double)w * (double)s_s[c];
        }
        out[0] = (float)(tot / (double)NVOX);
    }
}

// ---------------- fallback helpers (atomic path) ----------------
__global__ void ce_init(int* __restrict__ counts, float* __restrict__ sums) {
    int i = threadIdx.x;
    if (i < CC) { counts[i] = 0; sums[i] = 0.0f; }
}

__global__ void ce_finalize(const int* __restrict__ counts,
                            const float* __restrict__ sums,
                            float* __restrict__ out) {
    if (threadIdx.x == 0 && blockIdx.x == 0) {
        double tot = 0.0;
        for (int c = 0; c < CC; ++c) {
            const int n = counts[c];
            float w = 1.0f;
            if (n > 0) w = logf((float)NVOX / (float)n);
            tot += (double)w * (double)sums[c];
        }
        out[0] = (float)(tot / (double)NVOX);
    }
}

extern "C" void kernel_launch(void* const* d_in, const int* in_sizes, int n_in,
                              void* d_out, int out_size, void* d_ws, size_t ws_size,
                              hipStream_t stream) {
    const float* predict = (const float*)d_in[0];
    const float* target  = (const float*)d_in[1];
    float* out = (float*)d_out;

    const size_t need = (size_t)2 * CC * GRID * sizeof(float);  // 311 KB
    if (ws_size >= need) {
        int*   cnt_ws = (int*)d_ws;
        float* sum_ws = (float*)((char*)d_ws + (size_t)CC * GRID * sizeof(int));
        ce_pass1<true><<<GRID, BLOCK, 0, stream>>>(predict, target, cnt_ws, sum_ws);
        ce_reduce<<<1, BLOCK, 0, stream>>>(cnt_ws, sum_ws, out);
    } else {
        int*   counts = (int*)d_ws;
        float* sums   = (float*)d_ws + CC;
        ce_init<<<1, 64, 0, stream>>>(counts, sums);
        ce_pass1<false><<<GRID, BLOCK, 0, stream>>>(predict, target, counts, sums);
        ce_finalize<<<1, 64, 0, stream>>>(counts, sums, out);
    }
}